// Round 7
// baseline (32.154 us; speedup 1.0000x reference)
//
#include <hip/hip_runtime.h>
#include <math.h>

#define NOUT 64
#define NIN  64
#define HH   32
#define WW   32
#define CSTR 204                        // per-channel LDS plane: 6 rows * 34 cols
#define NBLK 512                        // 64 f * 8 bands

// block = (f, 4-row band); wave = 8-channel group; lane = (2-row pair, col);
// each lane owns 2 vertically-adjacent pixels; weights ride VMEM (broadcast loads)
__global__ __launch_bounds__(512, 6) void kan_main(const float* __restrict__ x,
                                                   const float* __restrict__ wn,
                                                   const float* __restrict__ wd,
                                                   float* __restrict__ out) {
    __shared__ float xt[NIN * CSTR];    // 52224 B; reused as reduction buffer

    // bijective XCD-chunked swizzle: 512 blocks, 64 per XCD -> 8 f's per XCD L2
    int bid  = blockIdx.x;
    int wgid = (bid & 7) * (NBLK / 8) + (bid >> 3);
    int f    = wgid >> 3;
    int band = wgid & 7;
    int i0   = band * 4;

    int tid = threadIdx.x;

    // ---- stage 6 rows x 34 cols x 64 c (rows i0-1 .. i0+4), coalesced global reads ----
    for (int k = 0; k < 26; ++k) {
        int idx = k * 512 + tid;        // idx = pos*64 + c
        if (idx < NIN * CSTR) {
            int c   = idx & 63;
            int pos = idx >> 6;         // 0..203
            int row = pos / 34;
            int col = pos % 34;
            int gi  = i0 - 1 + row;
            int gj  = col - 1;
            float v = 0.0f;
            if (gi >= 0 && gi < HH && gj >= 0 && gj < WW)
                v = x[(gi * WW + gj) * NIN + c];
            xt[c * CSTR + pos] = v;     // write 4-way alias (staging only)
        }
    }
    __syncthreads();

    int lane = tid & 63;
    int wv   = tid >> 6;                // c-group 0..7
    int r2   = lane >> 5;               // which 2-row pair
    int j    = lane & 31;               // col

    float acc0 = 0.0f, acc1 = 0.0f;
    int cbase = wv * 8;

    for (int cc = 0; cc < 8; ++cc) {
        int c = cbase + cc;

        // 12 window values: rows 2*r2 .. 2*r2+3 (staged-local), cols j..j+2
        const float* xb = &xt[c * CSTR + (r2 * 2) * 34 + j];
        float xw[4][3];
#pragma unroll
        for (int dr = 0; dr < 4; ++dr)
#pragma unroll
            for (int dc = 0; dc < 3; ++dc)
                xw[dr][dc] = xb[dr * 34 + dc];   // ds_read_b32, imm offsets, conflict-free

        size_t rec = (size_t)(f * NIN + c);
        const float2* wn2 = (const float2*)(wn + rec * 54);  // 8B-aligned
        const float4* wd4 = (const float4*)(wd + rec * 36);  // 16B-aligned

#pragma unroll
        for (int a = 0; a < 3; ++a) {
#pragma unroll
            for (int b = 0; b < 3; ++b) {
                const int ab = a * 3 + b;
                float2 A01 = wn2[ab * 3 + 0];    // a0 a1   (VMEM broadcast)
                float2 A23 = wn2[ab * 3 + 1];    // a2 a3
                float2 A45 = wn2[ab * 3 + 2];    // a4 a5
                float4 Bq  = wd4[ab];            // b0 b1 b2 b3
                {
                    float xv = xw[a][b];
                    float p = fmaf(A45.y, xv, A45.x);
                    p = fmaf(p, xv, A23.y);
                    p = fmaf(p, xv, A23.x);
                    p = fmaf(p, xv, A01.y);
                    p = fmaf(p, xv, A01.x);
                    float q = fmaf(Bq.w, xv, Bq.z);
                    q = fmaf(q, xv, Bq.y);
                    q = fmaf(q, xv, Bq.x);
                    float den = 1.0f + fabsf(xv * q);
                    acc0 = fmaf(p, __builtin_amdgcn_rcpf(den), acc0);
                }
                {
                    float xv = xw[a + 1][b];
                    float p = fmaf(A45.y, xv, A45.x);
                    p = fmaf(p, xv, A23.y);
                    p = fmaf(p, xv, A23.x);
                    p = fmaf(p, xv, A01.y);
                    p = fmaf(p, xv, A01.x);
                    float q = fmaf(Bq.w, xv, Bq.z);
                    q = fmaf(q, xv, Bq.y);
                    q = fmaf(q, xv, Bq.x);
                    float den = 1.0f + fabsf(xv * q);
                    acc1 = fmaf(p, __builtin_amdgcn_rcpf(den), acc1);
                }
            }
        }
    }

    // ---- cross-wave c-reduction; reuse xt as the buffer ----
    __syncthreads();
    float* red = xt;
    red[wv * 128 + (r2 * 2 + 0) * 32 + j] = acc0;
    red[wv * 128 + (r2 * 2 + 1) * 32 + j] = acc1;
    __syncthreads();
    if (tid < 128) {
        float s = 0.0f;
#pragma unroll
        for (int w = 0; w < 8; ++w) s += red[w * 128 + tid];
        out[f * (HH * WW) + (i0 + (tid >> 5)) * WW + (tid & 31)] = s;
    }
}

extern "C" void kernel_launch(void* const* d_in, const int* in_sizes, int n_in,
                              void* d_out, int out_size, void* d_ws, size_t ws_size,
                              hipStream_t stream) {
    const float* x  = (const float*)d_in[0];
    const float* wn = (const float*)d_in[1];
    const float* wd = (const float*)d_in[2];
    float* out = (float*)d_out;
    (void)d_ws; (void)ws_size; (void)in_sizes; (void)n_in; (void)out_size;

    kan_main<<<NBLK, 512, 0, stream>>>(x, wn, wd, out);
}